// Round 13
// baseline (381.528 us; speedup 1.0000x reference)
//
#include <hip/hip_runtime.h>
#include <math.h>

// LogicLayer: y[b,o] = prod_i ( a[b,i] + nw[o,i] - a[b,i]*nw[o,i] )
//   fw = sigmoid(W[o,i]) in (0,1); term = 1 - (1-a)*fw = fma(a-1, fw, 1).
// B=4096, OUT=256, IN=256, fp32.
//
// r13: r12 readout: S(forced SMEM)=13.1us/rep @VALUBusy 59.7% (stall 40%),
// P(plain)=24.7us/rep (2x worse -> dropped). Busy-time matches scalar-rate
// FMA -> builtin pk didn't pack (or pk is half-rate). This round:
//   - occupancy 2->4 waves/SIMD: 1024-thr blocks (16 waves), NOJ=4/thread,
//     grid 256 XCD-grouped, 66KB LDS (1 blk/CU).
//   - A/B: v_pk_fma_f32/v_pk_mul_f32 via inline asm  vs  builtin path.
// Same depth-1 SMEM pipeline, all lgkm ops in asm (compiler inserts no
// waits), WAITLGKM = lgkmcnt(0)+sched_barrier (rule #18).

#define IN_DIM 256
#define OUT_DIM 256
#define B_DIM 4096
#define BDIM 1024
#define ROWS 64
#define NOJ 4
#define OBLK 64  // 16 waves * NOJ
#define LDS_STRIDE 258

typedef float v2f __attribute__((ext_vector_type(2)));
typedef unsigned int u32x4 __attribute__((ext_vector_type(4)));

// ---- packed-fp32 ops: builtin path vs forced-asm path ----------------------
__device__ __forceinline__ v2f pk_fma_bi(v2f a, v2f b, v2f c) {
#if __has_builtin(__builtin_elementwise_fma)
  return __builtin_elementwise_fma(a, b, c);
#else
  v2f r;
  r.x = fmaf(a.x, b.x, c.x);
  r.y = fmaf(a.y, b.y, c.y);
  return r;
#endif
}
__device__ __forceinline__ v2f pk_mul_bi(v2f a, v2f b) { return a * b; }

__device__ __forceinline__ v2f pk_fma_asm(v2f a, v2f b, v2f c) {
  v2f d;
  asm("v_pk_fma_f32 %0, %1, %2, %3" : "=v"(d) : "v"(a), "v"(b), "v"(c));
  return d;
}
__device__ __forceinline__ v2f pk_mul_asm(v2f a, v2f b) {
  v2f d;
  asm("v_pk_mul_f32 %0, %1, %2" : "=v"(d) : "v"(a), "v"(b));
  return d;
}

template <bool ASMPK>
__device__ __forceinline__ v2f pk_fma(v2f a, v2f b, v2f c) {
  return ASMPK ? pk_fma_asm(a, b, c) : pk_fma_bi(a, b, c);
}
template <bool ASMPK>
__device__ __forceinline__ v2f pk_mul(v2f a, v2f b) {
  return ASMPK ? pk_mul_asm(a, b) : pk_mul_bi(a, b);
}

__device__ __forceinline__ float sigmoidf_dev(float x) {
  if (x >= 0.0f) {
    return 1.0f / (1.0f + expf(-x));
  }
  const float e = expf(x);
  return e / (1.0f + e);
}

// ---- Kernel 1: fw[t] = sigmoid(W[t]) ---------------------------------------
__global__ __launch_bounds__(256) void sigmoid_ew(const float* __restrict__ w,
                                                  float* __restrict__ fw) {
  const int t = blockIdx.x * 256 + threadIdx.x;
  fw[t] = sigmoidf_dev(w[t]);
}

// ---- asm building blocks (all in-loop lgkm ops live in asm) ----------------
#define ISSUE4(P, ADDR)                                                     \
  do {                                                                      \
    const unsigned long long _fa = (unsigned long long)(ADDR);              \
    asm volatile(                                                           \
        "s_load_dwordx4 %0, %4, 0x0\n\t"                                    \
        "s_load_dwordx4 %1, %4, 0x400\n\t"                                  \
        "s_load_dwordx4 %2, %4, 0x800\n\t"                                  \
        "s_load_dwordx4 %3, %4, 0xc00"                                      \
        : "=&s"(P##0), "=&s"(P##1), "=&s"(P##2), "=&s"(P##3)                \
        : "s"(_fa));                                                        \
  } while (0)

#define DSREAD(AM01, AM23, ADDRB)                                           \
  asm volatile("ds_read_b64 %0, %2\n\t"                                     \
               "ds_read_b64 %1, %2 offset:8"                                \
               : "=&v"(AM01), "=&v"(AM23)                                   \
               : "v"(ADDRB))

#define WAITLGKM()                                    \
  do {                                                \
    asm volatile("s_waitcnt lgkmcnt(0)");             \
    __builtin_amdgcn_sched_barrier(0);                \
  } while (0)

#define CONSUME4(P, AM01, AM23)                                  \
  do {                                                           \
    _Pragma("unroll") for (int j = 0; j < NOJ; ++j) {            \
      const u32x4 q = (j == 0) ? P##0                            \
                    : (j == 1) ? P##1                            \
                    : (j == 2) ? P##2 : P##3;                    \
      v2f f01, f23;                                              \
      f01.x = __uint_as_float(q[0]);                             \
      f01.y = __uint_as_float(q[1]);                             \
      f23.x = __uint_as_float(q[2]);                             \
      f23.y = __uint_as_float(q[3]);                             \
      const v2f t01 = pk_fma<ASMPK>(AM01, f01, ones);            \
      const v2f t23 = pk_fma<ASMPK>(AM23, f23, ones);            \
      prodv[j] = pk_mul<ASMPK>(prodv[j], pk_mul<ASMPK>(t01, t23)); \
    }                                                            \
  } while (0)

// ---- main: 1024 thr (16 waves = 4/SIMD), 64 b-rows x 64 o-cols -------------
template <int REPS, bool ASMPK>
__global__ __launch_bounds__(BDIM) void logic16(
    const float* __restrict__ atoms, const float* __restrict__ fw,
    float* __restrict__ out) {
  __shared__ float lds[ROWS * LDS_STRIDE];
  const int t = threadIdx.x;

  // XCD-grouped bijective remap: the 4 o-blocks of one bb share an XCD-L2.
  const int idx = blockIdx.x;       // [0,256)
  const int xcd = idx & 7;
  const int local = idx >> 3;       // [0,32)
  const int bb = xcd + 8 * (local >> 2);  // [0,64)
  const int ob = local & 3;               // [0,4)
  const int b0 = bb * ROWS;

  // stage am = atoms - 1 (4 float4 per thread, coalesced; row stride 258)
#pragma unroll
  for (int rnd = 0; rnd < 4; ++rnd) {
    const int e = rnd * 4096 + t * 4;
    const float4 v =
        *reinterpret_cast<const float4*>(atoms + (size_t)b0 * IN_DIM + e);
    const int row = e >> 8;
    const int col = e & 255;
    float* dst = &lds[row * LDS_STRIDE + col];
    v2f p0, p1;
    p0.x = v.x - 1.0f; p0.y = v.y - 1.0f;
    p1.x = v.z - 1.0f; p1.y = v.w - 1.0f;
    *reinterpret_cast<v2f*>(dst) = p0;
    *reinterpret_cast<v2f*>(dst + 2) = p1;
  }
  __syncthreads();

  const int r = t & 63;                                  // lane = b-row
  const int w = __builtin_amdgcn_readfirstlane(t >> 6);  // wave id 0..15
  const unsigned abase =
      (unsigned)(unsigned long long)(const void*)&lds[r * LDS_STRIDE];
  const int ocol0 = ob * OBLK + w * NOJ;
  const float* __restrict__ frow = fw + (size_t)ocol0 * IN_DIM;

  const v2f ones = {1.0f, 1.0f};
  v2f prodv[NOJ];

  u32x4 qa0, qa1, qa2, qa3;
  u32x4 qb0, qb1, qb2, qb3;
  v2f amA01, amA23, amB01, amB23;

#pragma unroll 1
  for (int rep = 0; rep < REPS; ++rep) {
#pragma unroll
    for (int j = 0; j < NOJ; ++j) prodv[j] = (v2f){1.0f, 1.0f};

    // prologue: quad-0 batch + am in flight (prev rep fully drained below)
    ISSUE4(qa, frow);
    DSREAD(amA01, amA23, abase);

#pragma unroll 1
    for (int i = 0; i < IN_DIM; i += 8) {
      const int iB = (i + 4) & 255;
      const int iA2 = (i + 8) & 255;

      WAITLGKM();                      // qa + amA ready
      ISSUE4(qb, frow + iB);           // next batch overlaps consume
      DSREAD(amB01, amB23, abase + (unsigned)iB * 4u);
      CONSUME4(qa, amA01, amA23);      // 16 pk ops

      WAITLGKM();                      // qb + amB ready
      ISSUE4(qa, frow + iA2);
      DSREAD(amA01, amA23, abase + (unsigned)iA2 * 4u);
      CONSUME4(qb, amB01, amB23);
    }
    WAITLGKM();  // drain trailing dummy issues before next rep / store
    // keep each rep observable (rule #17)
#pragma unroll
    for (int j = 0; j < NOJ; ++j) asm volatile("" : "+v"(prodv[j]));
  }

  float* op = out + (size_t)(b0 + r) * OUT_DIM + ocol0;
  float4 s;
  s.x = prodv[0].x * prodv[0].y;
  s.y = prodv[1].x * prodv[1].y;
  s.z = prodv[2].x * prodv[2].y;
  s.w = prodv[3].x * prodv[3].y;
  *reinterpret_cast<float4*>(op) = s;
}

// ---- fallback (no workspace): plain path, inline sigmoid -------------------
__global__ __launch_bounds__(512, 4) void logic_fallback(
    const float* __restrict__ atoms, const float* __restrict__ w_,
    float* __restrict__ out) {
  __shared__ float lds[ROWS * IN_DIM];
  const int t = threadIdx.x;
  const int bb = blockIdx.x >> 3;
  const int ob = blockIdx.x & 7;
  const int b0 = bb * ROWS;

#pragma unroll
  for (int rnd = 0; rnd < 8; ++rnd) {
    const int e = rnd * 2048 + t * 4;
    const int row = e >> 8;
    const int lane_u = (e & 255) >> 2;
    const int su = lane_u ^ (row & 7);
    const float4 v =
        *reinterpret_cast<const float4*>(atoms + (size_t)b0 * IN_DIM + e);
    float4 p;
    p.x = v.x - 1.0f; p.y = v.y - 1.0f;
    p.z = v.z - 1.0f; p.w = v.w - 1.0f;
    *reinterpret_cast<float4*>(&lds[row * IN_DIM + (su << 2)]) = p;
  }
  __syncthreads();

  const int r = t & 63;
  const int w = __builtin_amdgcn_readfirstlane(t >> 6);
  const int rm = r & 7;
  const float* rowbase = lds + r * IN_DIM;
  const int ocol0 = ob * 32 + w * 4;
  const float* __restrict__ frow = w_ + (size_t)ocol0 * IN_DIM;

  float prod[4];
#pragma unroll
  for (int j = 0; j < 4; ++j) prod[j] = 1.0f;

#pragma unroll 4
  for (int i = 0; i < IN_DIM; i += 4) {
    const float4 am4 = *reinterpret_cast<const float4*>(
        rowbase + ((((i >> 2) ^ rm)) << 2));
#pragma unroll
    for (int j = 0; j < 4; ++j) {
      float4 f4 = *reinterpret_cast<const float4*>(frow + j * IN_DIM + i);
      f4.x = sigmoidf_dev(f4.x);
      f4.y = sigmoidf_dev(f4.y);
      f4.z = sigmoidf_dev(f4.z);
      f4.w = sigmoidf_dev(f4.w);
      prod[j] *= fmaf(am4.x, f4.x, 1.0f) * fmaf(am4.y, f4.y, 1.0f) *
                 fmaf(am4.z, f4.z, 1.0f) * fmaf(am4.w, f4.w, 1.0f);
    }
  }

  float* op = out + (size_t)(b0 + r) * OUT_DIM + ocol0;
  float4 s;
  s.x = prod[0]; s.y = prod[1]; s.z = prod[2]; s.w = prod[3];
  *reinterpret_cast<float4*>(op) = s;
}

extern "C" void kernel_launch(void* const* d_in, const int* in_sizes, int n_in,
                              void* d_out, int out_size, void* d_ws,
                              size_t ws_size, hipStream_t stream) {
  const float* atoms = (const float*)d_in[0];    // [4096, 256]
  const float* weights = (const float*)d_in[1];  // [256, 256]
  float* out = (float*)d_out;                    // [4096, 256]

  if (ws_size >= (size_t)OUT_DIM * IN_DIM * sizeof(float)) {
    float* fw = (float*)d_ws;
    sigmoid_ew<<<dim3((OUT_DIM * IN_DIM) / 256), dim3(256), 0, stream>>>(
        weights, fw);
    // A/B at 4 waves/SIMD: forced v_pk_* asm vs builtin. Both x12 so both
    // clear the 41us fill threshold and surface in top-5 with counters.
    logic16<12, true><<<dim3(256), dim3(BDIM), 0, stream>>>(atoms, fw, out);
    logic16<12, false><<<dim3(256), dim3(BDIM), 0, stream>>>(atoms, fw, out);
  } else {
    logic_fallback<<<dim3(512), dim3(512), 0, stream>>>(atoms, weights, out);
  }
}